// Round 1
// baseline (1003.616 us; speedup 1.0000x reference)
//
#include <hip/hip_runtime.h>

#define N_NODES 1000000
#define N_EDGES 4000000
#define N_GRAPHS 1024
#define HIDDEN 64

__global__ __launch_bounds__(256) void k_init(int* __restrict__ deg,
                                              float4* __restrict__ s,
                                              float* __restrict__ out,
                                              const float* __restrict__ b2) {
    int i = blockIdx.x * blockDim.x + threadIdx.x;
    if (i < N_NODES) {
        deg[i] = 1;  // self-loop
        s[i] = make_float4(0.f, 0.f, 0.f, 0.f);
    }
    if (i < N_GRAPHS) out[i] = b2[0];
}

__global__ __launch_bounds__(256) void k_deg(const int* __restrict__ col,
                                             int* __restrict__ deg) {
    int e = blockIdx.x * blockDim.x + threadIdx.x;
    if (e < N_EDGES) atomicAdd(&deg[col[e]], 1);
}

__global__ __launch_bounds__(256) void k_dis(const int* __restrict__ deg,
                                             float* __restrict__ dis) {
    int i = blockIdx.x * blockDim.x + threadIdx.x;
    if (i < N_NODES) dis[i] = rsqrtf((float)deg[i]);
}

__global__ __launch_bounds__(256) void k_scatter(const int* __restrict__ row,
                                                 const int* __restrict__ col,
                                                 const float4* __restrict__ x,
                                                 const float* __restrict__ dis,
                                                 float* __restrict__ s) {
    int e = blockIdx.x * blockDim.x + threadIdx.x;
    if (e >= N_EDGES) return;
    int j = row[e];
    int i = col[e];
    float dj = dis[j];
    float4 xj = x[j];
    float* sp = s + 4ll * (long long)i;
    unsafeAtomicAdd(sp + 0, xj.x * dj);
    unsafeAtomicAdd(sp + 1, xj.y * dj);
    unsafeAtomicAdd(sp + 2, xj.z * dj);
    unsafeAtomicAdd(sp + 3, xj.w * dj);
}

__global__ __launch_bounds__(256) void k_node(const float4* __restrict__ x,
                                              const float4* __restrict__ s,
                                              const float* __restrict__ dis,
                                              const int* __restrict__ batch,
                                              const float* __restrict__ W1,
                                              const float* __restrict__ b1,
                                              const float* __restrict__ W2,
                                              float* __restrict__ out) {
    int n = blockIdx.x * blockDim.x + threadIdx.x;
    bool valid = n < N_NODES;
    float acc = 0.f;
    int g = -1;
    if (valid) {
        float4 xn = x[n];
        float4 sn = s[n];
        float di = dis[n];
        float inv = di * di;  // == 1/deg, self-loop norm
        float u0 = di * sn.x + inv * xn.x;
        float u1 = di * sn.y + inv * xn.y;
        float u2 = di * sn.z + inv * xn.z;
        float u3 = di * sn.w + inv * xn.w;
        g = batch[n];
        #pragma unroll
        for (int k = 0; k < HIDDEN; ++k) {
            // uniform indices -> compiler emits s_loads (SGPR operands, no LDS)
            float t = fmaf(u0, W1[k],
                      fmaf(u1, W1[HIDDEN + k],
                      fmaf(u2, W1[2 * HIDDEN + k],
                      fmaf(u3, W1[3 * HIDDEN + k], b1[k]))));
            float h = t > 0.f ? t : expm1f(t);
            acc = fmaf(h, W2[k], acc);
        }
    }
    // segmented wave reduction over sorted batch ids -> ~1 atomic per wave
    unsigned long long rem = __ballot(valid);
    while (rem) {
        int leader = __ffsll(rem) - 1;
        int gl = __shfl(g, leader);
        bool mine = valid && (g == gl);
        unsigned long long mask = __ballot(mine);
        float v = mine ? acc : 0.f;
        #pragma unroll
        for (int o = 32; o; o >>= 1) v += __shfl_xor(v, o);
        if ((int)(threadIdx.x & 63) == leader) unsafeAtomicAdd(&out[gl], v);
        rem &= ~mask;
    }
}

extern "C" void kernel_launch(void* const* d_in, const int* in_sizes, int n_in,
                              void* d_out, int out_size, void* d_ws, size_t ws_size,
                              hipStream_t stream) {
    const float* x   = (const float*)d_in[0];   // [N,4]
    const float* W1  = (const float*)d_in[1];   // [4,64]
    const float* b1  = (const float*)d_in[2];   // [64]
    const float* W2  = (const float*)d_in[3];   // [64,1]
    const float* b2  = (const float*)d_in[4];   // [1]
    const int*   ei  = (const int*)d_in[5];     // [2,E] (harness: integer -> int32)
    const int*   bat = (const int*)d_in[6];     // [N]
    float* out = (float*)d_out;                 // [1024]

    char* ws = (char*)d_ws;
    int*    deg = (int*)(ws);                       // 4 MB
    float*  dis = (float*)(ws + (size_t)N_NODES * 4);        // 4 MB
    float*  s   = (float*)(ws + (size_t)N_NODES * 8);        // 16 MB
    float4* s4  = (float4*)s;

    const int* row = ei;
    const int* col = ei + N_EDGES;

    int nb_n = (N_NODES + 255) / 256;
    int nb_e = (N_EDGES + 255) / 256;

    k_init<<<nb_n, 256, 0, stream>>>(deg, s4, out, b2);
    k_deg<<<nb_e, 256, 0, stream>>>(col, deg);
    k_dis<<<nb_n, 256, 0, stream>>>(deg, dis);
    k_scatter<<<nb_e, 256, 0, stream>>>(row, col, (const float4*)x, dis, s);
    k_node<<<nb_n, 256, 0, stream>>>((const float4*)x, s4, dis, bat, W1, b1, W2, out);
}

// Round 2
// 388.613 us; speedup vs baseline: 2.5826x; 2.5826x over previous
//
#include <hip/hip_runtime.h>

#define N_NODES 1000000
#define N_EDGES 4000000
#define N_GRAPHS 1024
#define HIDDEN 64
#define CHUNK 1024
#define NCHUNK ((N_NODES + CHUNK - 1) / CHUNK)  // 977

// ---------------- CSR (counting-sort) path ----------------

__global__ __launch_bounds__(256) void k_init_cnt(int* __restrict__ cnt,
                                                  float* __restrict__ out,
                                                  const float* __restrict__ b2) {
    int i = blockIdx.x * blockDim.x + threadIdx.x;
    if (i < N_NODES) cnt[i] = 0;
    if (i < N_GRAPHS) out[i] = b2[0];
}

__global__ __launch_bounds__(256) void k_rank(const int* __restrict__ col,
                                              int* __restrict__ cnt,
                                              int* __restrict__ rank) {
    int e = blockIdx.x * blockDim.x + threadIdx.x;
    if (e < N_EDGES) rank[e] = atomicAdd(&cnt[col[e]], 1);
}

// per-1024-chunk sums of cnt
__global__ __launch_bounds__(256) void k_scan1(const int* __restrict__ cnt,
                                               int* __restrict__ partials) {
    int b = blockIdx.x;
    int t = threadIdx.x;
    int n0 = b * CHUNK + t * 4;
    int s = 0;
    #pragma unroll
    for (int k = 0; k < 4; ++k) {
        int n = n0 + k;
        if (n < N_NODES) s += cnt[n];
    }
    #pragma unroll
    for (int o = 32; o; o >>= 1) s += __shfl_xor(s, o);
    __shared__ int w[4];
    if ((t & 63) == 0) w[t >> 6] = s;
    __syncthreads();
    if (t == 0) partials[b] = w[0] + w[1] + w[2] + w[3];
}

// exclusive scan of NCHUNK partials (single block, 1024 threads)
__global__ __launch_bounds__(1024) void k_scan2(const int* __restrict__ partials,
                                                int* __restrict__ chunk_base) {
    __shared__ int a[1024];
    int t = threadIdx.x;
    int v = (t < NCHUNK) ? partials[t] : 0;
    a[t] = v;
    __syncthreads();
    for (int o = 1; o < 1024; o <<= 1) {
        int u = (t >= o) ? a[t - o] : 0;
        __syncthreads();
        a[t] += u;
        __syncthreads();
    }
    if (t < NCHUNK) chunk_base[t] = a[t] - v;  // exclusive
}

// per-chunk: off = chunk_base + local exclusive scan; also dis, xd
__global__ __launch_bounds__(256) void k_scan3(const int* __restrict__ cnt,
                                               const int* __restrict__ chunk_base,
                                               const float4* __restrict__ x,
                                               int* __restrict__ off,
                                               float* __restrict__ dis,
                                               float4* __restrict__ xd) {
    int b = blockIdx.x;
    int t = threadIdx.x;
    int n0 = b * CHUNK + t * 4;
    int c[4];
    int p = 0;
    #pragma unroll
    for (int k = 0; k < 4; ++k) {
        int n = n0 + k;
        c[k] = (n < N_NODES) ? cnt[n] : 0;
    }
    int tot = c[0] + c[1] + c[2] + c[3];
    __shared__ int a[256];
    a[t] = tot;
    __syncthreads();
    for (int o = 1; o < 256; o <<= 1) {
        int u = (t >= o) ? a[t - o] : 0;
        __syncthreads();
        a[t] += u;
        __syncthreads();
    }
    int base = chunk_base[b] + a[t] - tot;  // exclusive within chunk + chunk base
    #pragma unroll
    for (int k = 0; k < 4; ++k) {
        int n = n0 + k;
        if (n < N_NODES) {
            off[n] = base + p;
            float d = rsqrtf((float)(c[k] + 1));
            dis[n] = d;
            float4 xn = x[n];
            xd[n] = make_float4(xn.x * d, xn.y * d, xn.z * d, xn.w * d);
        }
        p += c[k];
    }
}

__global__ __launch_bounds__(256) void k_place(const int* __restrict__ row,
                                               const int* __restrict__ col,
                                               const int* __restrict__ rank,
                                               const int* __restrict__ off,
                                               int* __restrict__ idx) {
    int e = blockIdx.x * blockDim.x + threadIdx.x;
    if (e >= N_EDGES) return;
    int c = col[e];
    idx[off[c] + rank[e]] = row[e];
}

__global__ __launch_bounds__(256) void k_final(const float4* __restrict__ xd,
                                               const float* __restrict__ dis,
                                               const int* __restrict__ off,
                                               const int* __restrict__ cnt,
                                               const int* __restrict__ idx,
                                               const int* __restrict__ batch,
                                               const float* __restrict__ W1,
                                               const float* __restrict__ b1,
                                               const float* __restrict__ W2,
                                               float* __restrict__ out) {
    int n = blockIdx.x * blockDim.x + threadIdx.x;
    bool valid = n < N_NODES;
    float acc = 0.f;
    int g = -1;
    if (valid) {
        float4 sum = xd[n];  // self-loop term
        int base = off[n];
        int c = cnt[n];
        for (int k = 0; k < c; ++k) {
            int j = idx[base + k];
            float4 v = xd[j];
            sum.x += v.x; sum.y += v.y; sum.z += v.z; sum.w += v.w;
        }
        float d = dis[n];
        float u0 = d * sum.x, u1 = d * sum.y, u2 = d * sum.z, u3 = d * sum.w;
        g = batch[n];
        #pragma unroll
        for (int k = 0; k < HIDDEN; ++k) {
            float t = fmaf(u0, W1[k],
                      fmaf(u1, W1[HIDDEN + k],
                      fmaf(u2, W1[2 * HIDDEN + k],
                      fmaf(u3, W1[3 * HIDDEN + k], b1[k]))));
            float h = t > 0.f ? t : expm1f(t);
            acc = fmaf(h, W2[k], acc);
        }
    }
    // segmented wave reduction over sorted batch ids -> ~1 atomic per wave
    unsigned long long rem = __ballot(valid);
    while (rem) {
        int leader = __ffsll(rem) - 1;
        int gl = __shfl(g, leader);
        bool mine = valid && (g == gl);
        unsigned long long mask = __ballot(mine);
        float v = mine ? acc : 0.f;
        #pragma unroll
        for (int o = 32; o; o >>= 1) v += __shfl_xor(v, o);
        if ((int)(threadIdx.x & 63) == leader) unsafeAtomicAdd(&out[gl], v);
        rem &= ~mask;
    }
}

// ---------------- fallback: original atomic-scatter path ----------------

__global__ __launch_bounds__(256) void k_init(int* __restrict__ deg,
                                              float4* __restrict__ s,
                                              float* __restrict__ out,
                                              const float* __restrict__ b2) {
    int i = blockIdx.x * blockDim.x + threadIdx.x;
    if (i < N_NODES) {
        deg[i] = 1;
        s[i] = make_float4(0.f, 0.f, 0.f, 0.f);
    }
    if (i < N_GRAPHS) out[i] = b2[0];
}

__global__ __launch_bounds__(256) void k_deg(const int* __restrict__ col,
                                             int* __restrict__ deg) {
    int e = blockIdx.x * blockDim.x + threadIdx.x;
    if (e < N_EDGES) atomicAdd(&deg[col[e]], 1);
}

__global__ __launch_bounds__(256) void k_dis(const int* __restrict__ deg,
                                             float* __restrict__ dis) {
    int i = blockIdx.x * blockDim.x + threadIdx.x;
    if (i < N_NODES) dis[i] = rsqrtf((float)deg[i]);
}

__global__ __launch_bounds__(256) void k_scatter(const int* __restrict__ row,
                                                 const int* __restrict__ col,
                                                 const float4* __restrict__ x,
                                                 const float* __restrict__ dis,
                                                 float* __restrict__ s) {
    int e = blockIdx.x * blockDim.x + threadIdx.x;
    if (e >= N_EDGES) return;
    int j = row[e];
    int i = col[e];
    float dj = dis[j];
    float4 xj = x[j];
    float* sp = s + 4ll * (long long)i;
    unsafeAtomicAdd(sp + 0, xj.x * dj);
    unsafeAtomicAdd(sp + 1, xj.y * dj);
    unsafeAtomicAdd(sp + 2, xj.z * dj);
    unsafeAtomicAdd(sp + 3, xj.w * dj);
}

__global__ __launch_bounds__(256) void k_node(const float4* __restrict__ x,
                                              const float4* __restrict__ s,
                                              const float* __restrict__ dis,
                                              const int* __restrict__ batch,
                                              const float* __restrict__ W1,
                                              const float* __restrict__ b1,
                                              const float* __restrict__ W2,
                                              float* __restrict__ out) {
    int n = blockIdx.x * blockDim.x + threadIdx.x;
    bool valid = n < N_NODES;
    float acc = 0.f;
    int g = -1;
    if (valid) {
        float4 xn = x[n];
        float4 sn = s[n];
        float di = dis[n];
        float inv = di * di;
        float u0 = di * sn.x + inv * xn.x;
        float u1 = di * sn.y + inv * xn.y;
        float u2 = di * sn.z + inv * xn.z;
        float u3 = di * sn.w + inv * xn.w;
        g = batch[n];
        #pragma unroll
        for (int k = 0; k < HIDDEN; ++k) {
            float t = fmaf(u0, W1[k],
                      fmaf(u1, W1[HIDDEN + k],
                      fmaf(u2, W1[2 * HIDDEN + k],
                      fmaf(u3, W1[3 * HIDDEN + k], b1[k]))));
            float h = t > 0.f ? t : expm1f(t);
            acc = fmaf(h, W2[k], acc);
        }
    }
    unsigned long long rem = __ballot(valid);
    while (rem) {
        int leader = __ffsll(rem) - 1;
        int gl = __shfl(g, leader);
        bool mine = valid && (g == gl);
        unsigned long long mask = __ballot(mine);
        float v = mine ? acc : 0.f;
        #pragma unroll
        for (int o = 32; o; o >>= 1) v += __shfl_xor(v, o);
        if ((int)(threadIdx.x & 63) == leader) unsafeAtomicAdd(&out[gl], v);
        rem &= ~mask;
    }
}

extern "C" void kernel_launch(void* const* d_in, const int* in_sizes, int n_in,
                              void* d_out, int out_size, void* d_ws, size_t ws_size,
                              hipStream_t stream) {
    const float* x   = (const float*)d_in[0];   // [N,4]
    const float* W1  = (const float*)d_in[1];   // [4,64]
    const float* b1  = (const float*)d_in[2];   // [64]
    const float* W2  = (const float*)d_in[3];   // [64,1]
    const float* b2  = (const float*)d_in[4];   // [1]
    const int*   ei  = (const int*)d_in[5];     // [2,E]
    const int*   bat = (const int*)d_in[6];     // [N]
    float* out = (float*)d_out;                 // [1024]

    const int* row = ei;
    const int* col = ei + N_EDGES;

    char* ws = (char*)d_ws;
    int nb_n = (N_NODES + 255) / 256;
    int nb_e = (N_EDGES + 255) / 256;

    // ws layout for CSR path
    size_t o_xd   = 0;                       // 16 MB  float4[N]
    size_t o_idx  = o_xd + 16000000;         // 16 MB  int[E]
    size_t o_rank = o_idx + 16000000;        // 16 MB  int[E]
    size_t o_cnt  = o_rank + 16000000;       // 4 MB   int[N]
    size_t o_off  = o_cnt + 4000000;         // 4 MB   int[N]
    size_t o_dis  = o_off + 4000000;         // 4 MB   float[N]
    size_t o_par  = o_dis + 4000000;         // partials + chunk_base
    size_t need   = o_par + 2 * sizeof(int) * ((size_t)NCHUNK + 64);

    if (ws_size >= need) {
        float4* xd        = (float4*)(ws + o_xd);
        int*    idx       = (int*)(ws + o_idx);
        int*    rank      = (int*)(ws + o_rank);
        int*    cnt       = (int*)(ws + o_cnt);
        int*    off       = (int*)(ws + o_off);
        float*  dis       = (float*)(ws + o_dis);
        int*    partials  = (int*)(ws + o_par);
        int*    chunk_bs  = partials + (NCHUNK + 64);

        k_init_cnt<<<nb_n, 256, 0, stream>>>(cnt, out, b2);
        k_rank<<<nb_e, 256, 0, stream>>>(col, cnt, rank);
        k_scan1<<<NCHUNK, 256, 0, stream>>>(cnt, partials);
        k_scan2<<<1, 1024, 0, stream>>>(partials, chunk_bs);
        k_scan3<<<NCHUNK, 256, 0, stream>>>(cnt, chunk_bs, (const float4*)x, off, dis, xd);
        k_place<<<nb_e, 256, 0, stream>>>(row, col, rank, off, idx);
        k_final<<<nb_n, 256, 0, stream>>>(xd, dis, off, cnt, idx, bat, W1, b1, W2, out);
    } else {
        // fallback: atomic scatter path (needs 24 MB)
        int*    deg = (int*)(ws);
        float*  dis = (float*)(ws + (size_t)N_NODES * 4);
        float*  s   = (float*)(ws + (size_t)N_NODES * 8);
        float4* s4  = (float4*)s;
        k_init<<<nb_n, 256, 0, stream>>>(deg, s4, out, b2);
        k_deg<<<nb_e, 256, 0, stream>>>(col, deg);
        k_dis<<<nb_n, 256, 0, stream>>>(deg, dis);
        k_scatter<<<nb_e, 256, 0, stream>>>(row, col, (const float4*)x, dis, s);
        k_node<<<nb_n, 256, 0, stream>>>((const float4*)x, s4, dis, bat, W1, b1, W2, out);
    }
}

// Round 3
// 210.566 us; speedup vs baseline: 4.7663x; 1.8456x over previous
//
#include <hip/hip_runtime.h>

#define N_NODES 1000000
#define N_EDGES 4000000
#define N_GRAPHS 1024
#define HIDDEN 64

#define G1 256                 // hist/partition blocks
#define T1 512                 // threads for hist/partition
#define EPB (N_EDGES / G1)     // 15625 edges per block (exact)
#define NB 256                 // bucket slots (245 used)
#define BSHIFT 12
#define BSIZE 4096
#define NBUSED ((N_NODES + BSIZE - 1) / BSIZE)  // 245

// ---- pass 1: per-block bucket histogram (LDS) + out init ----
__global__ __launch_bounds__(T1) void k_hist(const int* __restrict__ col,
                                             int* __restrict__ part,
                                             float* __restrict__ out,
                                             const float* __restrict__ b2) {
    __shared__ int h[NB];
    int t = threadIdx.x, blk = blockIdx.x;
    for (int i = t; i < NB; i += T1) h[i] = 0;
    int gid = blk * T1 + t;
    if (gid < N_GRAPHS) out[gid] = b2[0];
    __syncthreads();
    int e0 = blk * EPB;
    for (int i = t; i < EPB; i += T1) {
        int c = col[e0 + i];
        atomicAdd(&h[c >> BSHIFT], 1);
    }
    __syncthreads();
    for (int i = t; i < NB; i += T1) part[blk * NB + i] = h[i];
}

// ---- pass 2: turn counts into global (blk,bucket) start offsets ----
#define G2GROUPS 4
#define BLKS_PER_G (G1 / G2GROUPS)   // 64
__global__ __launch_bounds__(1024) void k_off(int* __restrict__ part,
                                              int* __restrict__ ebase,
                                              int* __restrict__ ecnt) {
    __shared__ int tot[G2GROUPS][NB];
    __shared__ int base[NB];
    __shared__ int sc[NB];
    int t = threadIdx.x;
    int q = t >> 8;        // group 0..3
    int b = t & 255;       // bucket
    int run = 0;
    for (int k = 0; k < BLKS_PER_G; ++k) {
        int blk = q * BLKS_PER_G + k;
        int v = part[blk * NB + b];
        part[blk * NB + b] = run;   // group-local exclusive prefix
        run += v;
    }
    tot[q][b] = run;
    __syncthreads();
    if (q == 0) {
        int t0 = tot[0][b], t1 = tot[1][b], t2 = tot[2][b], t3 = tot[3][b];
        int total = t0 + t1 + t2 + t3;
        ecnt[b] = total;
        tot[0][b] = 0;
        tot[1][b] = t0;
        tot[2][b] = t0 + t1;
        tot[3][b] = t0 + t1 + t2;
        sc[b] = total;
    }
    __syncthreads();
    for (int o = 1; o < NB; o <<= 1) {
        int v = 0;
        if (q == 0 && b >= o) v = sc[b - o];
        __syncthreads();
        if (q == 0) sc[b] += v;
        __syncthreads();
    }
    if (q == 0) {
        base[b] = sc[b] - ecnt[b];   // exclusive scan
        ebase[b] = base[b];
    }
    __syncthreads();
    for (int k = 0; k < BLKS_PER_G; ++k) {
        int blk = q * BLKS_PER_G + k;
        part[blk * NB + b] += tot[q][b] + base[b];
    }
}

// ---- pass 3: partition edges into buckets, packed 4B payload ----
__global__ __launch_bounds__(T1) void k_part(const int* __restrict__ row,
                                             const int* __restrict__ col,
                                             const int* __restrict__ part,
                                             unsigned* __restrict__ epair) {
    __shared__ int cur[NB];
    int t = threadIdx.x, blk = blockIdx.x;
    for (int i = t; i < NB; i += T1) cur[i] = part[blk * NB + i];
    __syncthreads();
    int e0 = blk * EPB;
    for (int i = t; i < EPB; i += T1) {
        int c = col[e0 + i];
        int r = row[e0 + i];
        int b = c >> BSHIFT;
        int pos = atomicAdd(&cur[b], 1);
        epair[pos] = ((unsigned)(c & (BSIZE - 1)) << 20) | (unsigned)r;
    }
}

// ---- pass 4: per-bucket degree (LDS), dis, xd = x*dis ----
__global__ __launch_bounds__(256) void k_deg2(const unsigned* __restrict__ epair,
                                              const int* __restrict__ ebase,
                                              const int* __restrict__ ecnt,
                                              const float4* __restrict__ x,
                                              float* __restrict__ dis,
                                              float4* __restrict__ xd) {
    __shared__ int deg[BSIZE];   // 16 KB
    int t = threadIdx.x, b = blockIdx.x;
    for (int i = t; i < BSIZE; i += 256) deg[i] = 1;   // self-loop
    __syncthreads();
    int e0 = ebase[b], ne = ecnt[b];
    for (int i = t; i < ne; i += 256) {
        unsigned u = epair[e0 + i];
        atomicAdd(&deg[u >> 20], 1);
    }
    __syncthreads();
    int n0 = b << BSHIFT;
    for (int i = t; i < BSIZE; i += 256) {
        int node = n0 + i;
        if (node < N_NODES) {
            float d = rsqrtf((float)deg[i]);
            dis[node] = d;
            float4 xv = x[node];
            xd[node] = make_float4(xv.x * d, xv.y * d, xv.z * d, xv.w * d);
        }
    }
}

// ---- pass 5: per-bucket gather + LDS accumulate + fused MLP/ELU/pool ----
__global__ __launch_bounds__(1024) void k_fin(const unsigned* __restrict__ epair,
                                              const int* __restrict__ ebase,
                                              const int* __restrict__ ecnt,
                                              const float4* __restrict__ xd,
                                              const float* __restrict__ dis,
                                              const int* __restrict__ batch,
                                              const float* __restrict__ W1,
                                              const float* __restrict__ b1,
                                              const float* __restrict__ W2,
                                              float* __restrict__ out) {
    __shared__ float4 s4[BSIZE];   // 64 KB
    int t = threadIdx.x, b = blockIdx.x;
    for (int i = t; i < BSIZE; i += 1024) s4[i] = make_float4(0.f, 0.f, 0.f, 0.f);
    __syncthreads();
    int e0 = ebase[b], ne = ecnt[b];
    for (int i = t; i < ne; i += 1024) {
        unsigned u = epair[e0 + i];
        int loc = u >> 20;
        int r = (int)(u & 0xFFFFFu);
        float4 v = xd[r];
        float* sp = (float*)&s4[loc];
        atomicAdd(sp + 0, v.x);
        atomicAdd(sp + 1, v.y);
        atomicAdd(sp + 2, v.z);
        atomicAdd(sp + 3, v.w);
    }
    __syncthreads();
    int n0 = b << BSHIFT;
    #pragma unroll
    for (int k = 0; k < BSIZE / 1024; ++k) {
        int ln = t + k * 1024;
        int node = n0 + ln;
        bool valid = node < N_NODES;
        float acc = 0.f;
        int g = -1;
        if (valid) {
            float4 sv = s4[ln];
            float4 xv = xd[node];   // self-loop term (already *dis)
            float d = dis[node];
            float u0 = d * (sv.x + xv.x);
            float u1 = d * (sv.y + xv.y);
            float u2 = d * (sv.z + xv.z);
            float u3 = d * (sv.w + xv.w);
            g = batch[node];
            #pragma unroll
            for (int kk = 0; kk < HIDDEN; ++kk) {
                float tt = fmaf(u0, W1[kk],
                           fmaf(u1, W1[HIDDEN + kk],
                           fmaf(u2, W1[2 * HIDDEN + kk],
                           fmaf(u3, W1[3 * HIDDEN + kk], b1[kk]))));
                float h = tt > 0.f ? tt : expm1f(tt);
                acc = fmaf(h, W2[kk], acc);
            }
        }
        unsigned long long rem = __ballot(valid);
        while (rem) {
            int leader = __ffsll(rem) - 1;
            int gl = __shfl(g, leader);
            bool mine = valid && (g == gl);
            unsigned long long mask = __ballot(mine);
            float v = mine ? acc : 0.f;
            #pragma unroll
            for (int o = 32; o; o >>= 1) v += __shfl_xor(v, o);
            if ((int)(t & 63) == leader) unsafeAtomicAdd(&out[gl], v);
            rem &= ~mask;
        }
    }
}

// ---------------- fallback: atomic-scatter path (small ws) ----------------
__global__ __launch_bounds__(256) void k_init(int* __restrict__ deg, float4* __restrict__ s,
                                              float* __restrict__ out, const float* __restrict__ b2) {
    int i = blockIdx.x * blockDim.x + threadIdx.x;
    if (i < N_NODES) { deg[i] = 1; s[i] = make_float4(0.f, 0.f, 0.f, 0.f); }
    if (i < N_GRAPHS) out[i] = b2[0];
}
__global__ __launch_bounds__(256) void k_deg(const int* __restrict__ col, int* __restrict__ deg) {
    int e = blockIdx.x * blockDim.x + threadIdx.x;
    if (e < N_EDGES) atomicAdd(&deg[col[e]], 1);
}
__global__ __launch_bounds__(256) void k_dis(const int* __restrict__ deg, float* __restrict__ dis) {
    int i = blockIdx.x * blockDim.x + threadIdx.x;
    if (i < N_NODES) dis[i] = rsqrtf((float)deg[i]);
}
__global__ __launch_bounds__(256) void k_scatter(const int* __restrict__ row, const int* __restrict__ col,
                                                 const float4* __restrict__ x, const float* __restrict__ dis,
                                                 float* __restrict__ s) {
    int e = blockIdx.x * blockDim.x + threadIdx.x;
    if (e >= N_EDGES) return;
    int j = row[e], i = col[e];
    float dj = dis[j];
    float4 xj = x[j];
    float* sp = s + 4ll * (long long)i;
    unsafeAtomicAdd(sp + 0, xj.x * dj);
    unsafeAtomicAdd(sp + 1, xj.y * dj);
    unsafeAtomicAdd(sp + 2, xj.z * dj);
    unsafeAtomicAdd(sp + 3, xj.w * dj);
}
__global__ __launch_bounds__(256) void k_node(const float4* __restrict__ x, const float4* __restrict__ s,
                                              const float* __restrict__ dis, const int* __restrict__ batch,
                                              const float* __restrict__ W1, const float* __restrict__ b1,
                                              const float* __restrict__ W2, float* __restrict__ out) {
    int n = blockIdx.x * blockDim.x + threadIdx.x;
    bool valid = n < N_NODES;
    float acc = 0.f; int g = -1;
    if (valid) {
        float4 xn = x[n], sn = s[n];
        float di = dis[n], inv = di * di;
        float u0 = di * sn.x + inv * xn.x, u1 = di * sn.y + inv * xn.y;
        float u2 = di * sn.z + inv * xn.z, u3 = di * sn.w + inv * xn.w;
        g = batch[n];
        #pragma unroll
        for (int k = 0; k < HIDDEN; ++k) {
            float t = fmaf(u0, W1[k], fmaf(u1, W1[HIDDEN + k],
                      fmaf(u2, W1[2 * HIDDEN + k], fmaf(u3, W1[3 * HIDDEN + k], b1[k]))));
            float h = t > 0.f ? t : expm1f(t);
            acc = fmaf(h, W2[k], acc);
        }
    }
    unsigned long long rem = __ballot(valid);
    while (rem) {
        int leader = __ffsll(rem) - 1;
        int gl = __shfl(g, leader);
        bool mine = valid && (g == gl);
        unsigned long long mask = __ballot(mine);
        float v = mine ? acc : 0.f;
        #pragma unroll
        for (int o = 32; o; o >>= 1) v += __shfl_xor(v, o);
        if ((int)(threadIdx.x & 63) == leader) unsafeAtomicAdd(&out[gl], v);
        rem &= ~mask;
    }
}

extern "C" void kernel_launch(void* const* d_in, const int* in_sizes, int n_in,
                              void* d_out, int out_size, void* d_ws, size_t ws_size,
                              hipStream_t stream) {
    const float* x   = (const float*)d_in[0];
    const float* W1  = (const float*)d_in[1];
    const float* b1  = (const float*)d_in[2];
    const float* W2  = (const float*)d_in[3];
    const float* b2  = (const float*)d_in[4];
    const int*   ei  = (const int*)d_in[5];
    const int*   bat = (const int*)d_in[6];
    float* out = (float*)d_out;

    const int* row = ei;
    const int* col = ei + N_EDGES;
    char* ws = (char*)d_ws;

    // ws layout (new path): ~36.3 MB
    size_t o_xd   = 0;                         // float4[N]  16 MB
    size_t o_ep   = o_xd + 16000000;           // uint[E]    16 MB
    size_t o_dis  = o_ep + 16000000;           // float[N]    4 MB
    size_t o_part = o_dis + 4000000;           // int[G1*NB] 256 KB
    size_t o_eb   = o_part + (size_t)G1 * NB * 4;
    size_t o_ec   = o_eb + NB * 4;
    size_t need   = o_ec + NB * 4;

    if (ws_size >= need) {
        float4*   xd    = (float4*)(ws + o_xd);
        unsigned* epair = (unsigned*)(ws + o_ep);
        float*    dis   = (float*)(ws + o_dis);
        int*      part  = (int*)(ws + o_part);
        int*      ebase = (int*)(ws + o_eb);
        int*      ecnt  = (int*)(ws + o_ec);

        k_hist<<<G1, T1, 0, stream>>>(col, part, out, b2);
        k_off<<<1, 1024, 0, stream>>>(part, ebase, ecnt);
        k_part<<<G1, T1, 0, stream>>>(row, col, part, epair);
        k_deg2<<<NBUSED, 256, 0, stream>>>(epair, ebase, ecnt, (const float4*)x, dis, xd);
        k_fin<<<NBUSED, 1024, 0, stream>>>(epair, ebase, ecnt, xd, dis, bat, W1, b1, W2, out);
    } else {
        int nb_n = (N_NODES + 255) / 256;
        int nb_e = (N_EDGES + 255) / 256;
        int*    deg = (int*)(ws);
        float*  dis = (float*)(ws + (size_t)N_NODES * 4);
        float*  s   = (float*)(ws + (size_t)N_NODES * 8);
        float4* s4  = (float4*)s;
        k_init<<<nb_n, 256, 0, stream>>>(deg, s4, out, b2);
        k_deg<<<nb_e, 256, 0, stream>>>(col, deg);
        k_dis<<<nb_n, 256, 0, stream>>>(deg, dis);
        k_scatter<<<nb_e, 256, 0, stream>>>(row, col, (const float4*)x, dis, s);
        k_node<<<nb_n, 256, 0, stream>>>((const float4*)x, s4, dis, bat, W1, b1, W2, out);
    }
}

// Round 4
// 198.895 us; speedup vs baseline: 5.0460x; 1.0587x over previous
//
#include <hip/hip_runtime.h>
#include <hip/hip_fp16.h>

#define N_NODES 1000000
#define N_EDGES 4000000
#define N_GRAPHS 1024
#define HIDDEN 64

#define G1 256                 // hist/partition blocks
#define T1 512                 // threads for hist/partition
#define EPB (N_EDGES / G1)     // 15625 edges per block (exact)
#define BSHIFT 11
#define BSIZE 2048
#define NBK 512                // bucket slots (489 used)
#define NBUCK ((N_NODES + BSIZE - 1) / BSIZE)  // 489

// ---- pass 1: per-block bucket histogram (LDS) + out init ----
__global__ __launch_bounds__(T1) void k_hist(const int* __restrict__ col,
                                             int* __restrict__ part,
                                             float* __restrict__ out,
                                             const float* __restrict__ b2) {
    __shared__ int h[NBK];
    int t = threadIdx.x, blk = blockIdx.x;
    for (int i = t; i < NBK; i += T1) h[i] = 0;
    int gid = blk * T1 + t;
    if (gid < N_GRAPHS) out[gid] = b2[0];
    __syncthreads();
    int e0 = blk * EPB;
    for (int i = t; i < EPB; i += T1) {
        int c = col[e0 + i];
        atomicAdd(&h[c >> BSHIFT], 1);
    }
    __syncthreads();
    for (int i = t; i < NBK; i += T1) part[blk * NBK + i] = h[i];
}

// ---- pass 2: counts -> global (blk,bucket) start offsets ----
__global__ __launch_bounds__(1024) void k_off(int* __restrict__ part,
                                              int* __restrict__ ebase,
                                              int* __restrict__ ecnt) {
    __shared__ int tot[2][NBK];
    __shared__ int sc[NBK];
    __shared__ int base[NBK];
    int t = threadIdx.x;
    int q = t >> 9;          // group 0..1 (128 blocks each)
    int b = t & (NBK - 1);
    int run = 0;
    for (int k = 0; k < G1 / 2; ++k) {
        int blk = q * (G1 / 2) + k;
        int v = part[blk * NBK + b];
        part[blk * NBK + b] = run;   // group-local exclusive prefix
        run += v;
    }
    tot[q][b] = run;
    __syncthreads();
    if (q == 0) {
        int t0 = tot[0][b], t1 = tot[1][b];
        ecnt[b] = t0 + t1;
        tot[0][b] = 0;
        tot[1][b] = t0;
        sc[b] = t0 + t1;
    }
    __syncthreads();
    for (int o = 1; o < NBK; o <<= 1) {
        int v = (q == 0 && b >= o) ? sc[b - o] : 0;
        __syncthreads();
        if (q == 0) sc[b] += v;
        __syncthreads();
    }
    if (q == 0) {
        base[b] = sc[b] - ecnt[b];   // exclusive
        ebase[b] = base[b];
    }
    __syncthreads();
    int add = tot[q][b] + base[b];
    for (int k = 0; k < G1 / 2; ++k) {
        int blk = q * (G1 / 2) + k;
        part[blk * NBK + b] += add;
    }
}

// ---- pass 3: partition edges, packed (colLocal<<20 | row) ----
__global__ __launch_bounds__(T1) void k_part(const int* __restrict__ row,
                                             const int* __restrict__ col,
                                             const int* __restrict__ part,
                                             unsigned* __restrict__ epair) {
    __shared__ int cur[NBK];
    int t = threadIdx.x, blk = blockIdx.x;
    for (int i = t; i < NBK; i += T1) cur[i] = part[blk * NBK + i];
    __syncthreads();
    int e0 = blk * EPB;
    for (int i = t; i < EPB; i += T1) {
        int c = col[e0 + i];
        int r = row[e0 + i];
        int b = c >> BSHIFT;
        int pos = atomicAdd(&cur[b], 1);
        epair[pos] = ((unsigned)(c & (BSIZE - 1)) << 20) | (unsigned)r;
    }
}

// ---- pass 4: per-bucket degree (LDS) -> dis (f32), xd (fp16x4) ----
__global__ __launch_bounds__(256) void k_deg2(const unsigned* __restrict__ epair,
                                              const int* __restrict__ ebase,
                                              const int* __restrict__ ecnt,
                                              const float4* __restrict__ x,
                                              float* __restrict__ dis,
                                              uint2* __restrict__ xdh) {
    __shared__ int deg[BSIZE];
    int t = threadIdx.x, b = blockIdx.x;
    for (int i = t; i < BSIZE; i += 256) deg[i] = 1;   // self-loop
    __syncthreads();
    int e0 = ebase[b], ne = ecnt[b];
    for (int i = t; i < ne; i += 256) {
        unsigned u = epair[e0 + i];
        atomicAdd(&deg[u >> 20], 1);
    }
    __syncthreads();
    int n0 = b << BSHIFT;
    for (int i = t; i < BSIZE; i += 256) {
        int node = n0 + i;
        if (node < N_NODES) {
            float d = rsqrtf((float)deg[i]);
            dis[node] = d;
            float4 xv = x[node];
            __half2 h01 = __floats2half2_rn(xv.x * d, xv.y * d);
            __half2 h23 = __floats2half2_rn(xv.z * d, xv.w * d);
            uint2 pk;
            pk.x = *(unsigned*)&h01;
            pk.y = *(unsigned*)&h23;
            xdh[node] = pk;
        }
    }
}

// ---- pass 5: per-bucket gather + LDS accumulate -> sbuf ----
__device__ __forceinline__ void acc_edge(unsigned u, uint2 p, float* sf) {
    int loc = u >> 20;
    __half2 h01 = *(__half2*)&p.x;
    __half2 h23 = *(__half2*)&p.y;
    float2 f01 = __half22float2(h01);
    float2 f23 = __half22float2(h23);
    float* sp = sf + loc * 5;        // stride 5: kills bank aliasing
    atomicAdd(sp + 0, f01.x);
    atomicAdd(sp + 1, f01.y);
    atomicAdd(sp + 2, f23.x);
    atomicAdd(sp + 3, f23.y);
}

__global__ __launch_bounds__(1024) void k_acc(const unsigned* __restrict__ epair,
                                              const int* __restrict__ ebase,
                                              const int* __restrict__ ecnt,
                                              const uint2* __restrict__ xdh,
                                              float4* __restrict__ sbuf) {
    __shared__ float sf[BSIZE * 5];   // 40 KB
    int t = threadIdx.x, b = blockIdx.x;
    for (int i = t; i < BSIZE * 5; i += 1024) sf[i] = 0.f;
    __syncthreads();
    int e0 = ebase[b], ne = ecnt[b];
    int ne4 = ne & ~3;
    const unsigned* ep = epair + e0;
    for (int i = 4 * t; i < ne4; i += 4096) {
        unsigned u0 = ep[i], u1 = ep[i + 1], u2 = ep[i + 2], u3 = ep[i + 3];
        uint2 p0 = xdh[u0 & 0xFFFFFu];
        uint2 p1 = xdh[u1 & 0xFFFFFu];
        uint2 p2 = xdh[u2 & 0xFFFFFu];
        uint2 p3 = xdh[u3 & 0xFFFFFu];
        acc_edge(u0, p0, sf);
        acc_edge(u1, p1, sf);
        acc_edge(u2, p2, sf);
        acc_edge(u3, p3, sf);
    }
    for (int i = ne4 + t; i < ne; i += 1024) {
        unsigned u = ep[i];
        acc_edge(u, xdh[u & 0xFFFFFu], sf);
    }
    __syncthreads();
    int n0 = b << BSHIFT;
    for (int i = t; i < BSIZE; i += 1024) {
        int node = n0 + i;
        if (node < N_NODES) {
            const float* sp = sf + i * 5;
            sbuf[node] = make_float4(sp[0], sp[1], sp[2], sp[3]);
        }
    }
}

// ---- pass 6: node-parallel MLP + ELU + pool ----
__global__ __launch_bounds__(256) void k_mlp(const float4* __restrict__ sbuf,
                                             const uint2* __restrict__ xdh,
                                             const float* __restrict__ dis,
                                             const int* __restrict__ batch,
                                             const float* __restrict__ W1,
                                             const float* __restrict__ b1,
                                             const float* __restrict__ W2,
                                             float* __restrict__ out) {
    int n = blockIdx.x * blockDim.x + threadIdx.x;
    bool valid = n < N_NODES;
    float acc = 0.f;
    int g = -1;
    if (valid) {
        float4 sv = sbuf[n];
        uint2 p = xdh[n];
        __half2 h01 = *(__half2*)&p.x;
        __half2 h23 = *(__half2*)&p.y;
        float2 f01 = __half22float2(h01);
        float2 f23 = __half22float2(h23);
        float d = dis[n];
        float u0 = d * (sv.x + f01.x);
        float u1 = d * (sv.y + f01.y);
        float u2 = d * (sv.z + f23.x);
        float u3 = d * (sv.w + f23.y);
        g = batch[n];
        #pragma unroll
        for (int k = 0; k < HIDDEN; ++k) {
            float t = fmaf(u0, W1[k],
                      fmaf(u1, W1[HIDDEN + k],
                      fmaf(u2, W1[2 * HIDDEN + k],
                      fmaf(u3, W1[3 * HIDDEN + k], b1[k]))));
            float h = t > 0.f ? t : (__expf(t) - 1.f);
            acc = fmaf(h, W2[k], acc);
        }
    }
    unsigned long long rem = __ballot(valid);
    while (rem) {
        int leader = __ffsll(rem) - 1;
        int gl = __shfl(g, leader);
        bool mine = valid && (g == gl);
        unsigned long long mask = __ballot(mine);
        float v = mine ? acc : 0.f;
        #pragma unroll
        for (int o = 32; o; o >>= 1) v += __shfl_xor(v, o);
        if ((int)(threadIdx.x & 63) == leader) unsafeAtomicAdd(&out[gl], v);
        rem &= ~mask;
    }
}

// ---------------- fallback: atomic-scatter path (small ws) ----------------
__global__ __launch_bounds__(256) void k_init(int* __restrict__ deg, float4* __restrict__ s,
                                              float* __restrict__ out, const float* __restrict__ b2) {
    int i = blockIdx.x * blockDim.x + threadIdx.x;
    if (i < N_NODES) { deg[i] = 1; s[i] = make_float4(0.f, 0.f, 0.f, 0.f); }
    if (i < N_GRAPHS) out[i] = b2[0];
}
__global__ __launch_bounds__(256) void k_deg(const int* __restrict__ col, int* __restrict__ deg) {
    int e = blockIdx.x * blockDim.x + threadIdx.x;
    if (e < N_EDGES) atomicAdd(&deg[col[e]], 1);
}
__global__ __launch_bounds__(256) void k_dis(const int* __restrict__ deg, float* __restrict__ dis) {
    int i = blockIdx.x * blockDim.x + threadIdx.x;
    if (i < N_NODES) dis[i] = rsqrtf((float)deg[i]);
}
__global__ __launch_bounds__(256) void k_scatter(const int* __restrict__ row, const int* __restrict__ col,
                                                 const float4* __restrict__ x, const float* __restrict__ dis,
                                                 float* __restrict__ s) {
    int e = blockIdx.x * blockDim.x + threadIdx.x;
    if (e >= N_EDGES) return;
    int j = row[e], i = col[e];
    float dj = dis[j];
    float4 xj = x[j];
    float* sp = s + 4ll * (long long)i;
    unsafeAtomicAdd(sp + 0, xj.x * dj);
    unsafeAtomicAdd(sp + 1, xj.y * dj);
    unsafeAtomicAdd(sp + 2, xj.z * dj);
    unsafeAtomicAdd(sp + 3, xj.w * dj);
}
__global__ __launch_bounds__(256) void k_node(const float4* __restrict__ x, const float4* __restrict__ s,
                                              const float* __restrict__ dis, const int* __restrict__ batch,
                                              const float* __restrict__ W1, const float* __restrict__ b1,
                                              const float* __restrict__ W2, float* __restrict__ out) {
    int n = blockIdx.x * blockDim.x + threadIdx.x;
    bool valid = n < N_NODES;
    float acc = 0.f; int g = -1;
    if (valid) {
        float4 xn = x[n], sn = s[n];
        float di = dis[n], inv = di * di;
        float u0 = di * sn.x + inv * xn.x, u1 = di * sn.y + inv * xn.y;
        float u2 = di * sn.z + inv * xn.z, u3 = di * sn.w + inv * xn.w;
        g = batch[n];
        #pragma unroll
        for (int k = 0; k < HIDDEN; ++k) {
            float t = fmaf(u0, W1[k], fmaf(u1, W1[HIDDEN + k],
                      fmaf(u2, W1[2 * HIDDEN + k], fmaf(u3, W1[3 * HIDDEN + k], b1[k]))));
            float h = t > 0.f ? t : expm1f(t);
            acc = fmaf(h, W2[k], acc);
        }
    }
    unsigned long long rem = __ballot(valid);
    while (rem) {
        int leader = __ffsll(rem) - 1;
        int gl = __shfl(g, leader);
        bool mine = valid && (g == gl);
        unsigned long long mask = __ballot(mine);
        float v = mine ? acc : 0.f;
        #pragma unroll
        for (int o = 32; o; o >>= 1) v += __shfl_xor(v, o);
        if ((int)(threadIdx.x & 63) == leader) unsafeAtomicAdd(&out[gl], v);
        rem &= ~mask;
    }
}

extern "C" void kernel_launch(void* const* d_in, const int* in_sizes, int n_in,
                              void* d_out, int out_size, void* d_ws, size_t ws_size,
                              hipStream_t stream) {
    const float* x   = (const float*)d_in[0];
    const float* W1  = (const float*)d_in[1];
    const float* b1  = (const float*)d_in[2];
    const float* W2  = (const float*)d_in[3];
    const float* b2  = (const float*)d_in[4];
    const int*   ei  = (const int*)d_in[5];
    const int*   bat = (const int*)d_in[6];
    float* out = (float*)d_out;

    const int* row = ei;
    const int* col = ei + N_EDGES;
    char* ws = (char*)d_ws;

    // ws layout: ~45 MB
    size_t o_ep   = 0;                          // uint[E]     16 MB
    size_t o_sb   = o_ep + 16000000;            // float4[N]   16 MB
    size_t o_xdh  = o_sb + 16000000;            // uint2[N]     8 MB
    size_t o_dis  = o_xdh + 8000000;            // float[N]     4 MB
    size_t o_part = o_dis + 4000000;            // int[G1*NBK] 512 KB
    size_t o_eb   = o_part + (size_t)G1 * NBK * 4;
    size_t o_ec   = o_eb + NBK * 4;
    size_t need   = o_ec + NBK * 4;

    if (ws_size >= need) {
        unsigned* epair = (unsigned*)(ws + o_ep);
        float4*   sbuf  = (float4*)(ws + o_sb);
        uint2*    xdh   = (uint2*)(ws + o_xdh);
        float*    dis   = (float*)(ws + o_dis);
        int*      part  = (int*)(ws + o_part);
        int*      ebase = (int*)(ws + o_eb);
        int*      ecnt  = (int*)(ws + o_ec);

        k_hist<<<G1, T1, 0, stream>>>(col, part, out, b2);
        k_off<<<1, 1024, 0, stream>>>(part, ebase, ecnt);
        k_part<<<G1, T1, 0, stream>>>(row, col, part, epair);
        k_deg2<<<NBUCK, 256, 0, stream>>>(epair, ebase, ecnt, (const float4*)x, dis, xdh);
        k_acc<<<NBUCK, 1024, 0, stream>>>(epair, ebase, ecnt, xdh, sbuf);
        k_mlp<<<(N_NODES + 255) / 256, 256, 0, stream>>>(sbuf, xdh, dis, bat, W1, b1, W2, out);
    } else {
        int nb_n = (N_NODES + 255) / 256;
        int nb_e = (N_EDGES + 255) / 256;
        int*    deg = (int*)(ws);
        float*  dis = (float*)(ws + (size_t)N_NODES * 4);
        float*  s   = (float*)(ws + (size_t)N_NODES * 8);
        float4* s4  = (float4*)s;
        k_init<<<nb_n, 256, 0, stream>>>(deg, s4, out, b2);
        k_deg<<<nb_e, 256, 0, stream>>>(col, deg);
        k_dis<<<nb_n, 256, 0, stream>>>(deg, dis);
        k_scatter<<<nb_e, 256, 0, stream>>>(row, col, (const float4*)x, dis, s);
        k_node<<<nb_n, 256, 0, stream>>>((const float4*)x, s4, dis, bat, W1, b1, W2, out);
    }
}